// Round 8
// baseline (69.345 us; speedup 1.0000x reference)
//
#include <hip/hip_runtime.h>

// FP8 e4m3 (IEEE variant, top exponent excluded -> max level 240) fake-quantization:
//   ema = max|x| (whole tensor), s = max(ema/240, 1e-8)
//   xq  = nearest_level(x/s) * s   (ties -> lower-valued level)
//
// Level grid: uniform step 2^(e-3) per binade (clamped to 2^-9 in the subnormal
// region); top binade [128, 240] step 16. All steps are powers of two, so
// nearest-level = ceil(v/step - 0.5) * step with every intermediate exact in f32
// (ties -> lower level = argmin first occurrence). x/s uses IEEE div to bit-match
// the reference's x_scaled (reciprocal-multiply can flip a top-binade near-tie:
// one level there = 16*s ~ 0.36 > 0.108 threshold).
//
// Structure (2 plain kernels):
//   - cooperative grid.sync costs 3.3x per-byte (R6: 850 GB/s vs 7 TB/s) -> no fusion
//   - single-address atomics serialize ~15ns each (R2: 8192 atomics = 125us) -> no
//     atomic barrier; per-block partials + redundant reduce in kernel B instead.
//   A: per-block absmax -> partials[block] (plain store per block).
//   B: every block reduces the 2048 partials (8 KB, L2-hot, <1us) -> s, then
//      quantizes with NON-TEMPORAL stores so the 134 MB output doesn't evict x
//      from the 256 MB L3 (keeps next replay's absmax read L3-resident).

typedef float f32x4 __attribute__((ext_vector_type(4)));

#define FP8Q_THREADS 256
#define FP8Q_MAXBLOCKS 2048

__global__ __launch_bounds__(FP8Q_THREADS) void fp8q_absmax_kernel(
    const f32x4* __restrict__ x4, float* __restrict__ partials,
    const float* __restrict__ x_tail, int n4, int ntail)
{
    __shared__ float smem[FP8Q_THREADS / 64];
    int tid = blockIdx.x * blockDim.x + threadIdx.x;
    int stride = gridDim.x * blockDim.x;

    // 2-way unrolled grid-stride: two independent 16B loads in flight per iter
    float ma = 0.0f, mb = 0.0f;
    int i = tid;
    for (; i + stride < n4; i += 2 * stride) {
        f32x4 a = x4[i];
        f32x4 b = x4[i + stride];
        ma = fmaxf(ma, fmaxf(fmaxf(fabsf(a.x), fabsf(a.y)),
                             fmaxf(fabsf(a.z), fabsf(a.w))));
        mb = fmaxf(mb, fmaxf(fmaxf(fabsf(b.x), fabsf(b.y)),
                             fmaxf(fabsf(b.z), fabsf(b.w))));
    }
    if (i < n4) {
        f32x4 a = x4[i];
        ma = fmaxf(ma, fmaxf(fmaxf(fabsf(a.x), fabsf(a.y)),
                             fmaxf(fabsf(a.z), fabsf(a.w))));
    }
    float m = fmaxf(ma, mb);
    if (tid < ntail) m = fmaxf(m, fabsf(x_tail[tid]));  // leftover (<4) elements

    #pragma unroll
    for (int off = 32; off > 0; off >>= 1)
        m = fmaxf(m, __shfl_xor(m, off));
    if ((threadIdx.x & 63) == 0) smem[threadIdx.x >> 6] = m;
    __syncthreads();
    if (threadIdx.x == 0) {
        float mm = smem[0];
        #pragma unroll
        for (int w = 1; w < FP8Q_THREADS / 64; ++w) mm = fmaxf(mm, smem[w]);
        partials[blockIdx.x] = mm;   // one plain store per block
    }
}

__device__ __forceinline__ float fp8q_quant1(float x, float s)
{
    float v = x / s;                               // IEEE div: bit-matches reference x/s
    v = fminf(fmaxf(v, -240.0f), 240.0f);          // saturate at max level (E=1..14 only)
    float m = fabsf(v);
    int e  = (int)(__float_as_uint(m) >> 23) - 127; // unbiased exponent (m=0 -> -127)
    int se = e - 3;                                 // step = 2^(e-3) within binade
    if (se < -9) se = -9;                           // subnormal region: uniform step 2^-9
    float step     = __uint_as_float((unsigned int)(se + 127) << 23);
    float inv_step = __uint_as_float((unsigned int)(127 - se) << 23);
    float k = v * inv_step;                         // exact (pow2 scale), |k| <= 16
    float n = ceilf(k - 0.5f);                      // round-half-to-lower-value (ref tie rule)
    return (n * step) * s;                          // n*step is exactly the level
}

__device__ __forceinline__ f32x4 fp8q_quant4(f32x4 v, float s)
{
    f32x4 r;
    r.x = fp8q_quant1(v.x, s);
    r.y = fp8q_quant1(v.y, s);
    r.z = fp8q_quant1(v.z, s);
    r.w = fp8q_quant1(v.w, s);
    return r;
}

__global__ __launch_bounds__(FP8Q_THREADS) void fp8q_quant_kernel(
    const f32x4* __restrict__ x4, f32x4* __restrict__ o4,
    const float* __restrict__ x_tail, float* __restrict__ o_tail,
    const float* __restrict__ partials, int np, int n4, int ntail)
{
    __shared__ float smem[FP8Q_THREADS / 64];
    __shared__ float s_shared;
    // redundant per-block reduce of block partials (scalar, L2-hot, <1us)
    float m = 0.0f;
    for (int i = threadIdx.x; i < np; i += FP8Q_THREADS)
        m = fmaxf(m, partials[i]);
    #pragma unroll
    for (int off = 32; off > 0; off >>= 1)
        m = fmaxf(m, __shfl_xor(m, off));
    if ((threadIdx.x & 63) == 0) smem[threadIdx.x >> 6] = m;
    __syncthreads();
    if (threadIdx.x == 0) {
        float mm = smem[0];
        #pragma unroll
        for (int w = 1; w < FP8Q_THREADS / 64; ++w) mm = fmaxf(mm, smem[w]);
        s_shared = fmaxf(mm / 240.0f, 1e-8f);      // 240 + 1e-12 == 240.0f in f32
    }
    __syncthreads();
    float s = s_shared;

    int tid = blockIdx.x * blockDim.x + threadIdx.x;
    int stride = gridDim.x * blockDim.x;

    // 2-way unrolled: two independent load->quant->NT-store pairs in flight
    int i = tid;
    for (; i + stride < n4; i += 2 * stride) {
        f32x4 a = x4[i];
        f32x4 b = x4[i + stride];
        f32x4 ra = fp8q_quant4(a, s);
        f32x4 rb = fp8q_quant4(b, s);
        __builtin_nontemporal_store(ra, &o4[i]);
        __builtin_nontemporal_store(rb, &o4[i + stride]);
    }
    if (i < n4) {
        f32x4 a = x4[i];
        __builtin_nontemporal_store(fp8q_quant4(a, s), &o4[i]);
    }
    if (tid < ntail) o_tail[tid] = fp8q_quant1(x_tail[tid], s);
}

extern "C" void kernel_launch(void* const* d_in, const int* in_sizes, int n_in,
                              void* d_out, int out_size, void* d_ws, size_t ws_size,
                              hipStream_t stream)
{
    const float* x = (const float*)d_in[0];
    float* out = (float*)d_out;
    int n = in_sizes[0];
    int n4 = n >> 2;
    int ntail = n & 3;
    const float* x_tail = x + (size_t)n4 * 4;
    float* o_tail = out + (size_t)n4 * 4;

    float* partials = (float*)d_ws;   // one float per block

    int blocks = (n4 + FP8Q_THREADS - 1) / FP8Q_THREADS;
    if (blocks > FP8Q_MAXBLOCKS) blocks = FP8Q_MAXBLOCKS;
    if (blocks < 1) blocks = 1;

    fp8q_absmax_kernel<<<blocks, FP8Q_THREADS, 0, stream>>>(
        (const f32x4*)x, partials, x_tail, n4, ntail);
    fp8q_quant_kernel<<<blocks, FP8Q_THREADS, 0, stream>>>(
        (const f32x4*)x, (f32x4*)out, x_tail, o_tail, partials, blocks, n4, ntail);
}

// Round 9
// 68.341 us; speedup vs baseline: 1.0147x; 1.0147x over previous
//
#include <hip/hip_runtime.h>

// FP8 e4m3 (IEEE variant, top exponent excluded -> max level 240) fake-quantization:
//   ema = max|x| (whole tensor), s = max(ema/240, 1e-8)
//   xq  = nearest_level(x/s) * s   (ties -> lower-valued level)
//
// Level grid: uniform step 2^(e-3) per binade (clamped to 2^-9 in the subnormal
// region); top binade [128, 240] step 16. All steps are powers of two, so
// nearest-level = ceil(v/step - 0.5) * step with every intermediate exact in f32
// (ties -> lower level = argmin first occurrence). x/s uses IEEE div to bit-match
// the reference's x_scaled (reciprocal-multiply can flip a top-binade near-tie:
// one level there = 16*s ~ 0.36 > 0.108 threshold; slack is only 0.018).
//
// Structure (2 plain kernels):
//   - cooperative grid.sync costs 3.3x per-byte (R6: 850 GB/s vs 7 TB/s) -> no fusion
//   - single-address atomics serialize ~15ns each (R2: 8192 atomics = 125us) -> no
//     atomic barrier; per-block partials + redundant reduce in kernel B instead.
//   A: per-block absmax -> partials[block] (plain store per block). 2-way unrolled
//     (best measured).
//   B: every block reduces the 2048 partials (8 KB, L2-hot, <1us) -> s, then
//      quantizes. R9 A/B: REGULAR stores (R4-R8 used nontemporal; testing whether
//      nt bypasses the write-combining path that gives fill kernels 7 TB/s).

typedef float f32x4 __attribute__((ext_vector_type(4)));

#define FP8Q_THREADS 256
#define FP8Q_MAXBLOCKS 2048

__global__ __launch_bounds__(FP8Q_THREADS) void fp8q_absmax_kernel(
    const f32x4* __restrict__ x4, float* __restrict__ partials,
    const float* __restrict__ x_tail, int n4, int ntail)
{
    __shared__ float smem[FP8Q_THREADS / 64];
    int tid = blockIdx.x * blockDim.x + threadIdx.x;
    int stride = gridDim.x * blockDim.x;

    // 2-way unrolled grid-stride: two independent 16B loads in flight per iter
    float ma = 0.0f, mb = 0.0f;
    int i = tid;
    for (; i + stride < n4; i += 2 * stride) {
        f32x4 a = x4[i];
        f32x4 b = x4[i + stride];
        ma = fmaxf(ma, fmaxf(fmaxf(fabsf(a.x), fabsf(a.y)),
                             fmaxf(fabsf(a.z), fabsf(a.w))));
        mb = fmaxf(mb, fmaxf(fmaxf(fabsf(b.x), fabsf(b.y)),
                             fmaxf(fabsf(b.z), fabsf(b.w))));
    }
    if (i < n4) {
        f32x4 a = x4[i];
        ma = fmaxf(ma, fmaxf(fmaxf(fabsf(a.x), fabsf(a.y)),
                             fmaxf(fabsf(a.z), fabsf(a.w))));
    }
    float m = fmaxf(ma, mb);
    if (tid < ntail) m = fmaxf(m, fabsf(x_tail[tid]));  // leftover (<4) elements

    #pragma unroll
    for (int off = 32; off > 0; off >>= 1)
        m = fmaxf(m, __shfl_xor(m, off));
    if ((threadIdx.x & 63) == 0) smem[threadIdx.x >> 6] = m;
    __syncthreads();
    if (threadIdx.x == 0) {
        float mm = smem[0];
        #pragma unroll
        for (int w = 1; w < FP8Q_THREADS / 64; ++w) mm = fmaxf(mm, smem[w]);
        partials[blockIdx.x] = mm;   // one plain store per block
    }
}

__device__ __forceinline__ float fp8q_quant1(float x, float s)
{
    float v = x / s;                               // IEEE div: bit-matches reference x/s
    v = fminf(fmaxf(v, -240.0f), 240.0f);          // saturate at max level (E=1..14 only)
    float m = fabsf(v);
    int e  = (int)(__float_as_uint(m) >> 23) - 127; // unbiased exponent (m=0 -> -127)
    int se = e - 3;                                 // step = 2^(e-3) within binade
    if (se < -9) se = -9;                           // subnormal region: uniform step 2^-9
    float step     = __uint_as_float((unsigned int)(se + 127) << 23);
    float inv_step = __uint_as_float((unsigned int)(127 - se) << 23);
    float k = v * inv_step;                         // exact (pow2 scale), |k| <= 16
    float n = ceilf(k - 0.5f);                      // round-half-to-lower-value (ref tie rule)
    return (n * step) * s;                          // n*step is exactly the level
}

__global__ __launch_bounds__(FP8Q_THREADS) void fp8q_quant_kernel(
    const f32x4* __restrict__ x4, f32x4* __restrict__ o4,
    const float* __restrict__ x_tail, float* __restrict__ o_tail,
    const float* __restrict__ partials, int np, int n4, int ntail)
{
    __shared__ float smem[FP8Q_THREADS / 64];
    __shared__ float s_shared;
    // redundant per-block reduce of block partials (scalar, L2-hot, <1us)
    float m = 0.0f;
    for (int i = threadIdx.x; i < np; i += FP8Q_THREADS)
        m = fmaxf(m, partials[i]);
    #pragma unroll
    for (int off = 32; off > 0; off >>= 1)
        m = fmaxf(m, __shfl_xor(m, off));
    if ((threadIdx.x & 63) == 0) smem[threadIdx.x >> 6] = m;
    __syncthreads();
    if (threadIdx.x == 0) {
        float mm = smem[0];
        #pragma unroll
        for (int w = 1; w < FP8Q_THREADS / 64; ++w) mm = fmaxf(mm, smem[w]);
        s_shared = fmaxf(mm / 240.0f, 1e-8f);      // 240 + 1e-12 == 240.0f in f32
    }
    __syncthreads();
    float s = s_shared;

    int tid = blockIdx.x * blockDim.x + threadIdx.x;
    int stride = gridDim.x * blockDim.x;
    for (int i = tid; i < n4; i += stride) {
        f32x4 v = x4[i];
        f32x4 r;
        r.x = fp8q_quant1(v.x, s);
        r.y = fp8q_quant1(v.y, s);
        r.z = fp8q_quant1(v.z, s);
        r.w = fp8q_quant1(v.w, s);
        o4[i] = r;                                  // regular store (R9 A/B vs nt)
    }
    if (tid < ntail) o_tail[tid] = fp8q_quant1(x_tail[tid], s);
}

extern "C" void kernel_launch(void* const* d_in, const int* in_sizes, int n_in,
                              void* d_out, int out_size, void* d_ws, size_t ws_size,
                              hipStream_t stream)
{
    const float* x = (const float*)d_in[0];
    float* out = (float*)d_out;
    int n = in_sizes[0];
    int n4 = n >> 2;
    int ntail = n & 3;
    const float* x_tail = x + (size_t)n4 * 4;
    float* o_tail = out + (size_t)n4 * 4;

    float* partials = (float*)d_ws;   // one float per block

    int blocks = (n4 + FP8Q_THREADS - 1) / FP8Q_THREADS;
    if (blocks > FP8Q_MAXBLOCKS) blocks = FP8Q_MAXBLOCKS;
    if (blocks < 1) blocks = 1;

    fp8q_absmax_kernel<<<blocks, FP8Q_THREADS, 0, stream>>>(
        (const f32x4*)x, partials, x_tail, n4, ntail);
    fp8q_quant_kernel<<<blocks, FP8Q_THREADS, 0, stream>>>(
        (const f32x4*)x, (f32x4*)out, x_tail, o_tail, partials, blocks, n4, ntail);
}